// Round 6
// baseline (205.801 us; speedup 1.0000x reference)
//
#include <hip/hip_runtime.h>
#include <hip/hip_bf16.h>
#include <stdint.h>

#define AS1 __attribute__((address_space(1)))
#define AS3 __attribute__((address_space(3)))

typedef __attribute__((ext_vector_type(8))) short short8;
typedef __attribute__((ext_vector_type(4))) float f32x4;
typedef __attribute__((ext_vector_type(4))) int i32x4;
typedef __attribute__((ext_vector_type(16))) int i32x16;

__device__ __forceinline__ unsigned short f2bf(float f) {
  return __builtin_bit_cast(unsigned short, __float2bfloat16(f));
}

// ---------------------------------------------------------------------------
// Kernel 1 (fused quant prep): one block per matrix row.
// Blocks [0, wrows): FWHT-128 on W row (fp32, in-register) -> row absmax ->
//   i8 quantize -> Wq, s_w[row].
// Blocks [wrows, ...): x row absmax -> i8 quantize -> Xq, s_x[row].
// ---------------------------------------------------------------------------
__global__ __launch_bounds__(256) void quant_prep(const float* __restrict__ W,
                                                  signed char* __restrict__ Wq,
                                                  float* __restrict__ sw,
                                                  const float* __restrict__ x,
                                                  signed char* __restrict__ Xq,
                                                  float* __restrict__ sx,
                                                  int wrows, int Kd) {
  __shared__ float red[4];
  const int bid = blockIdx.x;
  const int tid = threadIdx.x;
  const bool isW = bid < wrows;
  const int row = isW ? bid : bid - wrows;
  const float* src = (isW ? W : x) + (size_t)row * Kd + tid * 16;

  float v[16];
  {
    float4 f0 = ((const float4*)src)[0];
    float4 f1 = ((const float4*)src)[1];
    float4 f2 = ((const float4*)src)[2];
    float4 f3 = ((const float4*)src)[3];
    v[0] = f0.x; v[1] = f0.y; v[2] = f0.z; v[3] = f0.w;
    v[4] = f1.x; v[5] = f1.y; v[6] = f1.z; v[7] = f1.w;
    v[8] = f2.x; v[9] = f2.y; v[10] = f2.z; v[11] = f2.w;
    v[12] = f3.x; v[13] = f3.y; v[14] = f3.z; v[15] = f3.w;
  }

  if (isW) {
    // FWHT-128: thread holds 16 contiguous elems (bits 0..3); a 128-segment
    // spans 8 threads (bits 4..6 = tid&7), all within one wave.
#pragma unroll
    for (int m = 1; m <= 8; m <<= 1) {
#pragma unroll
      for (int j = 0; j < 16; ++j) {
        if ((j & m) == 0) {
          float lo = v[j], hi = v[j + m];
          v[j] = lo + hi;
          v[j + m] = lo - hi;
        }
      }
    }
    const int g = tid & 7;
#pragma unroll
    for (int m = 1; m <= 4; m <<= 1) {
#pragma unroll
      for (int j = 0; j < 16; ++j) {
        float p = __shfl_xor(v[j], m, 64);
        v[j] = (g & m) ? (p - v[j]) : (v[j] + p);
      }
    }
    const float s = 0.08838834764831845f; // 1/sqrt(128)
#pragma unroll
    for (int j = 0; j < 16; ++j) v[j] *= s;
  }

  // row absmax: wave reduce then block reduce (4 waves)
  float am = 0.f;
#pragma unroll
  for (int j = 0; j < 16; ++j) am = fmaxf(am, fabsf(v[j]));
#pragma unroll
  for (int m = 1; m < 64; m <<= 1) am = fmaxf(am, __shfl_xor(am, m, 64));
  if ((tid & 63) == 0) red[tid >> 6] = am;
  __syncthreads();
  am = fmaxf(fmaxf(red[0], red[1]), fmaxf(red[2], red[3]));

  const float inv = (am > 1e-30f) ? (127.0f / am) : 0.f;
  union { uint4 u; signed char c[16]; } pk;
#pragma unroll
  for (int j = 0; j < 16; ++j) {
    float q = __builtin_rintf(v[j] * inv);
    q = fminf(127.f, fmaxf(-127.f, q));
    pk.c[j] = (signed char)(int)q;
  }
  signed char* dst = (isW ? Wq : Xq) + (size_t)row * Kd + tid * 16;
  *(uint4*)dst = pk.u;
  if (tid == 0) (isW ? sw : sx)[row] = am / 127.0f;
}

// ---------------------------------------------------------------------------
__device__ __forceinline__ void gload16(const void* g, void* l) {
  __builtin_amdgcn_global_load_lds((const AS1 unsigned int*)g,
                                   (AS3 unsigned int*)l, 16, 0, 0);
}

// ---------------------------------------------------------------------------
// Kernel 2: i8 GEMM — R0's proven 256^2 4-phase read-ahead schedule VERBATIM
// (staging, swizzle, vmcnt/lgkm ledger, barriers identical; 0 bank conflicts
// proven), with EXACTLY ONE variable changed: MFMA shape 16x16x64 ->
// mfma_i32_32x32x32_i8 (m55: 4404 vs m16: 3944 TOPS ubench).
//
// R5 post-mortem motivation: all 3 structure families (2w/SIMD R0, 4w/SIMD
// R1-R3, 1w/SIMD bigwave R5) land at 2.0-2.3x the 16x16x64-i8 ubench floor
// -- R1/R5 EXCEED the full-DS-serialization bound, so scheduling cannot be
// the limiter. Model: 16x16x64_i8 sustains ~40 cyc in-kernel (bf16-equal),
// and R0 is ~90% of that effective pipe. This build discriminates: same
// FLOPs, same ds_read bytes AND instruction count (24 b128/K-tile), same
// ledger; only the MFMA shape + fragment mapping changes. Integer math is
// bit-identical -> absmax must stay 0.09375 (a layout error fails loudly).
//
// Fragments (analogy verified by the working 16x16 kernel + m74/m101 C/D):
//   A/B: row|col = lane&31, k = (lane>>5)*16 + j  (16 contiguous bytes)
//   C/D: col = lane&31, row = (reg&3) + 8*(reg>>2) + 4*(lane>>5)
// K-tile 128 = 2 kh-planes x 2 ks-halves = 4 quadrants; per quadrant per
// wave: 4 A-frags (128 rows/32) + 2 B-frags (64 cols/32) = 6 ds_read_b128,
// 8 MFMA. ks=1 addr = ks=0 addr ^ 32 (bit5 is 0 pre-swizzle; XOR-safe).
// Dequant epilogue: out = sx[m]*sw[n]*acc + b[n] (integer accum is exact).
// ---------------------------------------------------------------------------
#define BM 256
#define BN 256
#define PL(base_, mat_, kh_) ((base_) + (((mat_) * 2 + (kh_)) * 16384))

__global__ __launch_bounds__(512, 2) void gemm256_i8(const signed char* __restrict__ Xq,
                                                     const signed char* __restrict__ Wq,
                                                     const float* __restrict__ sx,
                                                     const float* __restrict__ sw,
                                                     const float* __restrict__ bias,
                                                     float* __restrict__ out,
                                                     int M, int N, int K) {
  __shared__ __align__(16) char lds[131072];

  const int tid = threadIdx.x;
  const int lane = tid & 63;
  const int wid = tid >> 6; // 0..7
  const int wm = wid >> 2;  // 0..1 (128-row strip)
  const int wn = wid & 3;   // 0..3 (64-col strip)

  // XCD bijective swizzle (gridDim.x = 512, multiple of 8)
  const int nwg = gridDim.x;
  const int cpx = nwg >> 3;
  const int swz = (blockIdx.x & 7) * cpx + (blockIdx.x >> 3);
  const int nbn = N / BN;
  const int m0 = (swz / nbn) * BM;
  const int n0 = (swz % nbn) * BN;

  const size_t Kb = (size_t)K; // 1 byte/elem

  // ---- stage source pointers: pre-swizzled global (rule #21) ----
  const int dphys0 = tid * 16;
  const int dphys1 = tid * 16 + 8192;
  const char* srcA[2][2]; // [kh][rd]
  const char* srcB[2][2];
  {
    const int dv[2] = {dphys0, dphys1};
#pragma unroll
    for (int rd = 0; rd < 2; ++rd) {
      const int d = dv[rd];
      const int l = d ^ (((d >> 7) & 3) << 4); // involution: bits 7,8 untouched
      const int row = l >> 6;
      const int cb = l & 63;
#pragma unroll
      for (int kh = 0; kh < 2; ++kh) {
        srcA[kh][rd] = (const char*)Xq + (size_t)(m0 + row) * Kb + kh * 64 + cb;
        srcB[kh][rd] = (const char*)Wq + (size_t)(n0 + row) * Kb + kh * 64 + cb;
      }
    }
  }

  // ---- swizzled in-plane ds_read offsets (same involution) ----
  const int ln31 = lane & 31; // frag row/col within 32
  const int hi = lane >> 5;   // k-subchunk select (16 B)
  int oA[4], oAx[4], oB[2], oBx[2];
#pragma unroll
  for (int mi = 0; mi < 4; ++mi) {
    int row = wm * 128 + mi * 32 + ln31; // 0..255
    int byt = row * 64 + hi * 16;
    oA[mi] = byt ^ (((byt >> 7) & 3) << 4);
    oAx[mi] = oA[mi] ^ 32; // ks=1 half (bit5 pre-swz is 0 -> XOR == select)
  }
#pragma unroll
  for (int ni = 0; ni < 2; ++ni) {
    int row = wn * 64 + ni * 32 + ln31; // 0..255
    int byt = row * 64 + hi * 16;
    oB[ni] = byt ^ (((byt >> 7) & 3) << 4);
    oBx[ni] = oB[ni] ^ 32;
  }

  i32x16 acc[4][2];
#pragma unroll
  for (int i = 0; i < 4; ++i)
#pragma unroll
    for (int j = 0; j < 2; ++j)
      acc[i][j] = (i32x16){0, 0, 0, 0, 0, 0, 0, 0, 0, 0, 0, 0, 0, 0, 0, 0};

  const int NT = K / 128; // 32 (K-tile = 128 i8 = 128 B/row)
  char* const lb0 = lds;
  char* const lb1 = lds + 65536;

#define STAGE(mat_, kh_, base_, toff_)                                       \
  do {                                                                       \
    const char* s0_ = ((mat_) ? srcB : srcA)[kh_][0] + (toff_);              \
    const char* s1_ = ((mat_) ? srcB : srcA)[kh_][1] + (toff_);              \
    gload16(s0_, PL(base_, mat_, kh_) + dphys0);                             \
    gload16(s1_, PL(base_, mat_, kh_) + dphys1);                             \
  } while (0)

// read one quadrant (kh, ks): 4 A-frags + 2 B-frags = 6 ds_read_b128
#define READQ(av_, bv_, base_, kh_, oA_, oB_)                                \
  do {                                                                       \
    const char* pa_ = PL(base_, 0, kh_);                                     \
    const char* pb_ = PL(base_, 1, kh_);                                     \
    _Pragma("unroll") for (int mi = 0; mi < 4; ++mi)                         \
        av_[mi] = *(const i32x4*)(pa_ + oA_[mi]);                            \
    _Pragma("unroll") for (int ni = 0; ni < 2; ++ni)                         \
        bv_[ni] = *(const i32x4*)(pb_ + oB_[ni]);                            \
  } while (0)

#define MFMA8(a_, b_)                                                        \
  do {                                                                       \
    __builtin_amdgcn_s_setprio(1);                                           \
    _Pragma("unroll") for (int mi = 0; mi < 4; ++mi)                         \
        _Pragma("unroll") for (int ni = 0; ni < 2; ++ni)                     \
            acc[mi][ni] = __builtin_amdgcn_mfma_i32_32x32x32_i8(             \
                a_[mi], b_[ni], acc[mi][ni], 0, 0, 0);                       \
    __builtin_amdgcn_s_setprio(0);                                           \
    __builtin_amdgcn_sched_barrier(0);                                       \
  } while (0)

#define LGKM(n_)                                                             \
  asm volatile("s_waitcnt lgkmcnt(" #n_ ")" ::: "memory");                   \
  __builtin_amdgcn_sched_barrier(0)

  // ---- prologue: stage kh0(0), kh1(0), kh0(1) = 12 loads; confirm tile 0 ----
  gload16(srcA[0][0], PL(lb0, 0, 0) + dphys0);
  gload16(srcA[0][1], PL(lb0, 0, 0) + dphys1);
  gload16(srcB[0][0], PL(lb0, 1, 0) + dphys0);
  gload16(srcB[0][1], PL(lb0, 1, 0) + dphys1);
  gload16(srcA[1][0], PL(lb0, 0, 1) + dphys0);
  gload16(srcA[1][1], PL(lb0, 0, 1) + dphys1);
  gload16(srcB[1][0], PL(lb0, 1, 1) + dphys0);
  gload16(srcB[1][1], PL(lb0, 1, 1) + dphys1);
  gload16(srcA[0][0] + 128, PL(lb1, 0, 0) + dphys0);
  gload16(srcA[0][1] + 128, PL(lb1, 0, 0) + dphys1);
  gload16(srcB[0][0] + 128, PL(lb1, 1, 0) + dphys0);
  gload16(srcB[0][1] + 128, PL(lb1, 1, 0) + dphys1);
  asm volatile("s_waitcnt vmcnt(4)" ::: "memory"); // tile 0 fully landed
  __builtin_amdgcn_s_barrier();
  asm volatile("" ::: "memory");

  i32x4 avC[4], bvC[2], avN[4], bvN[2];
  READQ(avC, bvC, lb0, 0, oA, oB); // Q0(0) = (kh0, ks0)

  for (int t = 0; t < NT; ++t) {
    char* const cb = (t & 1) ? lb1 : lb0; // current buffer
    char* const db = (t & 1) ? lb0 : lb1; // other buffer
    int tn1 = t + 1; if (tn1 >= NT) tn1 -= NT; // ring wrap
    int tn2 = t + 2; if (tn2 >= NT) tn2 -= NT;
    const size_t toff1 = (size_t)tn1 * 128; // 128 B per K-tile
    const size_t toff2 = (size_t)tn2 * 128;

    // p0: MFMA Q0(avC); read Q1=(kh0,ks1)->N; stage A-kh1(t+1)->d
    __builtin_amdgcn_s_barrier();
    asm volatile("" ::: "memory");
    READQ(avN, bvN, cb, 0, oAx, oBx);
    STAGE(0, 1, db, toff1);
    LGKM(6);
    MFMA8(avC, bvC);

    // p1: vmcnt(6) confirms kh1(t); read Q2=(kh1,ks0)->C; stage B-kh1(t+1)->d
    asm volatile("s_waitcnt vmcnt(6)" ::: "memory");
    __builtin_amdgcn_s_barrier();
    asm volatile("" ::: "memory");
    READQ(avC, bvC, cb, 1, oA, oB);
    STAGE(1, 1, db, toff1);
    LGKM(6);
    MFMA8(avN, bvN);

    // p2: read Q3=(kh1,ks1)->N; stage A-kh0(t+2)->c (kh0 reads drained)
    __builtin_amdgcn_s_barrier();
    asm volatile("" ::: "memory");
    READQ(avN, bvN, cb, 1, oAx, oBx);
    STAGE(0, 0, cb, toff2);
    LGKM(6);
    MFMA8(avC, bvC);

    // p3: vmcnt(6) confirms kh0(t+1); read Q0(t+1)->C from buf d
    asm volatile("s_waitcnt vmcnt(6)" ::: "memory");
    __builtin_amdgcn_s_barrier();
    asm volatile("" ::: "memory");
    READQ(avC, bvC, db, 0, oA, oB);
    STAGE(1, 0, cb, toff2);
    LGKM(6);
    MFMA8(avN, bvN);
  }
  asm volatile("s_waitcnt vmcnt(0)" ::: "memory"); // drain ring stages

  // ---- epilogue: 32x32 C/D: col=lane&31, row=(reg&3)+8*(reg>>2)+4*(lane>>5);
  // dequant out = sx[row]*sw[col]*acc + b[col], fp32 store.
  const int orow = m0 + wm * 128;
  const int ocol = n0 + wn * 64;
  float swv[2], bcv[2];
#pragma unroll
  for (int ni = 0; ni < 2; ++ni) {
    const int col = ocol + ni * 32 + ln31;
    swv[ni] = sw[col];
    bcv[ni] = bias[col];
  }
#pragma unroll
  for (int mi = 0; mi < 4; ++mi) {
#pragma unroll
    for (int r = 0; r < 16; ++r) {
      const int row = orow + mi * 32 + (r & 3) + ((r >> 2) << 3) + (hi << 2);
      const float sxr = sx[row];
      float* rowp = out + (size_t)row * N;
#pragma unroll
      for (int ni = 0; ni < 2; ++ni) {
        rowp[ocol + ni * 32 + ln31] =
            (float)acc[mi][ni][r] * (sxr * swv[ni]) + bcv[ni];
      }
    }
  }
#undef STAGE
#undef READQ
#undef MFMA8
#undef LGKM
}

// ---------------------------------------------------------------------------
// Fallback (small workspace): bf16 path — standalone FWHT + 128^2 GEMM.
// ---------------------------------------------------------------------------
__global__ __launch_bounds__(256) void fwht_only(const float* __restrict__ W,
                                                 unsigned short* __restrict__ Wp,
                                                 int total_vec) {
  int t = blockIdx.x * blockDim.x + threadIdx.x;
  if (t >= total_vec) return;
  float4 r0 = ((const float4*)W)[2 * t];
  float4 r1 = ((const float4*)W)[2 * t + 1];
  float v[8] = {r0.x, r0.y, r0.z, r0.w, r1.x, r1.y, r1.z, r1.w};
#pragma unroll
  for (int m = 1; m <= 4; m <<= 1) {
#pragma unroll
    for (int j = 0; j < 8; ++j) {
      if ((j & m) == 0) {
        float lo = v[j], hi = v[j + m];
        v[j] = lo + hi;
        v[j + m] = lo - hi;
      }
    }
  }
  const int g = t & 15;
#pragma unroll
  for (int m = 1; m <= 8; m <<= 1) {
#pragma unroll
    for (int j = 0; j < 8; ++j) {
      float p = __shfl_xor(v[j], m, 64);
      v[j] = (g & m) ? (p - v[j]) : (v[j] + p);
    }
  }
  const float s = 0.08838834764831845f;
  uint4 outv;
  unsigned short* ou = (unsigned short*)&outv;
#pragma unroll
  for (int j = 0; j < 8; ++j) ou[j] = f2bf(v[j] * s);
  ((uint4*)Wp)[t] = outv;
}

__global__ __launch_bounds__(256) void gemm128_a32(const float* __restrict__ X,
                                                   const unsigned short* __restrict__ Wp,
                                                   const float* __restrict__ bias,
                                                   float* __restrict__ out,
                                                   int M, int N, int K) {
  __shared__ __align__(16) unsigned short lA[128 * 32];
  __shared__ __align__(16) unsigned short lB[128 * 32];
  const int tid = threadIdx.x;
  const int lane = tid & 63;
  const int wid = tid >> 6;
  const int wr = wid >> 1, wc = wid & 1;
  const int nbn = N / 128;
  const int bm = blockIdx.x / nbn, bn = blockIdx.x % nbn;
  const int m0 = bm * 128, n0 = bn * 128;
  f32x4 acc[4][4];
#pragma unroll
  for (int i = 0; i < 4; ++i)
#pragma unroll
    for (int j = 0; j < 4; ++j) acc[i][j] = (f32x4){0.f, 0.f, 0.f, 0.f};
  const size_t Kb = (size_t)K * 2;
  const int off0 = tid * 16, off1 = off0 + 4096;
  const int r0 = off0 >> 6, c0 = off0 & 63;
  const int r1 = off1 >> 6, c1 = off1 & 63;
  const char* Bg0 = (const char*)Wp + (size_t)(n0 + r0) * Kb + c0;
  const char* Bg1 = (const char*)Wp + (size_t)(n0 + r1) * Kb + c1;
  char* lB0 = (char*)lB + off0;
  char* lB1 = (char*)lB + off1;
  const int arow = tid >> 1;
  const int acol = (tid & 1) * 16;
  const float* Af = X + (size_t)(m0 + arow) * K + acol;
  unsigned short* lAw = &lA[arow * 32 + acol];
  const int fr = lane & 15;
  const int kc = (lane >> 4) << 3;
  const unsigned short* pA = &lA[(wr * 64 + fr) * 32 + kc];
  const unsigned short* pB = &lB[(wc * 64 + fr) * 32 + kc];
  for (int k0 = 0; k0 < K; k0 += 32) {
    const int kb = k0 << 1;
    gload16(Bg0 + kb, lB0);
    gload16(Bg1 + kb, lB1);
    const float* src = Af + k0;
    float4 f0 = *(const float4*)(src + 0);
    float4 f1 = *(const float4*)(src + 4);
    float4 f2 = *(const float4*)(src + 8);
    float4 f3 = *(const float4*)(src + 12);
    union { uint4 u[2]; unsigned short s[16]; } pk;
    float vv[16] = {f0.x, f0.y, f0.z, f0.w, f1.x, f1.y, f1.z, f1.w,
                    f2.x, f2.y, f2.z, f2.w, f3.x, f3.y, f3.z, f3.w};
#pragma unroll
    for (int j = 0; j < 16; ++j) pk.s[j] = f2bf(vv[j]);
    ((uint4*)lAw)[0] = pk.u[0];
    ((uint4*)(lAw + 8))[0] = pk.u[1];
    __syncthreads();
    short8 af[4], bfr[4];
#pragma unroll
    for (int mi = 0; mi < 4; ++mi) af[mi] = *(const short8*)(pA + mi * 16 * 32);
#pragma unroll
    for (int ni = 0; ni < 4; ++ni) bfr[ni] = *(const short8*)(pB + ni * 16 * 32);
#pragma unroll
    for (int mi = 0; mi < 4; ++mi)
#pragma unroll
      for (int ni = 0; ni < 4; ++ni)
        acc[mi][ni] = __builtin_amdgcn_mfma_f32_16x16x32_bf16(af[mi], bfr[ni],
                                                              acc[mi][ni], 0, 0, 0);
    __syncthreads();
  }
  const int orow0 = m0 + wr * 64;
  const int ocol0 = n0 + wc * 64;
  const int rsub = (lane >> 4) << 2;
#pragma unroll
  for (int ni = 0; ni < 4; ++ni) {
    const int col = ocol0 + ni * 16 + fr;
    const float bc = bias[col];
#pragma unroll
    for (int mi = 0; mi < 4; ++mi)
#pragma unroll
      for (int r = 0; r < 4; ++r)
        out[(size_t)(orow0 + mi * 16 + rsub + r) * N + col] = acc[mi][ni][r] + bc;
  }
}

// ---------------------------------------------------------------------------
extern "C" void kernel_launch(void* const* d_in, const int* in_sizes, int n_in,
                              void* d_out, int out_size, void* d_ws, size_t ws_size,
                              hipStream_t stream) {
  const float* x = (const float*)d_in[0];
  const float* W = (const float*)d_in[1];
  const float* b = (const float*)d_in[2];
  float* out = (float*)d_out;

  const int O = in_sizes[2];     // 4096
  const int K = in_sizes[1] / O; // 4096
  const int M = in_sizes[0] / K; // 8192

  const size_t wqB = (size_t)O * K;       // i8 W'
  const size_t xqB = (size_t)M * K;       // i8 x
  const size_t need = wqB + xqB + (size_t)(O + M) * 4 + 256;

  if (ws_size >= need) {
    signed char* Wq = (signed char*)d_ws;
    signed char* Xq = (signed char*)d_ws + wqB;
    float* sw = (float*)((char*)d_ws + wqB + xqB);
    float* sx = sw + O;
    quant_prep<<<O + M, 256, 0, stream>>>(W, Wq, sw, x, Xq, sx, O, K);
    dim3 grid((M / BM) * (O / BN)); // 32*16 = 512, %8 == 0
    gemm256_i8<<<grid, 512, 0, stream>>>(Xq, Wq, sx, sw, b, out, M, O, K);
  } else {
    unsigned short* Wp = (unsigned short*)d_ws;
    const int wvec = (O * K) / 8;
    fwht_only<<<(wvec + 255) / 256, 256, 0, stream>>>(W, Wp, wvec);
    dim3 grid((M / 128) * (O / 128));
    gemm128_a32<<<grid, 256, 0, stream>>>(x, Wp, b, out, M, O, K);
  }
}

// Round 7
// 198.291 us; speedup vs baseline: 1.0379x; 1.0379x over previous
//
#include <hip/hip_runtime.h>
#include <hip/hip_bf16.h>
#include <stdint.h>

#define AS1 __attribute__((address_space(1)))
#define AS3 __attribute__((address_space(3)))

typedef __attribute__((ext_vector_type(8))) short short8;
typedef __attribute__((ext_vector_type(4))) float f32x4;
typedef __attribute__((ext_vector_type(4))) int i32x4;

__device__ __forceinline__ unsigned short f2bf(float f) {
  return __builtin_bit_cast(unsigned short, __float2bfloat16(f));
}

// ---------------------------------------------------------------------------
// Kernel 1 (fused quant prep): one block per matrix row.
// Blocks [0, wrows): FWHT-128 on W row (fp32, in-register) -> row absmax ->
//   i8 quantize -> Wq, s_w[row].
// Blocks [wrows, ...): x row absmax -> i8 quantize -> Xq, s_x[row].
// 256 thr x 16 elems = 4096 elems/row. Exact per-row absmax => no clipping;
// error is pure rounding (~0.9% rms per element).
// ---------------------------------------------------------------------------
__global__ __launch_bounds__(256) void quant_prep(const float* __restrict__ W,
                                                  signed char* __restrict__ Wq,
                                                  float* __restrict__ sw,
                                                  const float* __restrict__ x,
                                                  signed char* __restrict__ Xq,
                                                  float* __restrict__ sx,
                                                  int wrows, int Kd) {
  __shared__ float red[4];
  const int bid = blockIdx.x;
  const int tid = threadIdx.x;
  const bool isW = bid < wrows;
  const int row = isW ? bid : bid - wrows;
  const float* src = (isW ? W : x) + (size_t)row * Kd + tid * 16;

  float v[16];
  {
    float4 f0 = ((const float4*)src)[0];
    float4 f1 = ((const float4*)src)[1];
    float4 f2 = ((const float4*)src)[2];
    float4 f3 = ((const float4*)src)[3];
    v[0] = f0.x; v[1] = f0.y; v[2] = f0.z; v[3] = f0.w;
    v[4] = f1.x; v[5] = f1.y; v[6] = f1.z; v[7] = f1.w;
    v[8] = f2.x; v[9] = f2.y; v[10] = f2.z; v[11] = f2.w;
    v[12] = f3.x; v[13] = f3.y; v[14] = f3.z; v[15] = f3.w;
  }

  if (isW) {
    // FWHT-128: thread holds 16 contiguous elems (bits 0..3); a 128-segment
    // spans 8 threads (bits 4..6 = tid&7), all within one wave.
#pragma unroll
    for (int m = 1; m <= 8; m <<= 1) {
#pragma unroll
      for (int j = 0; j < 16; ++j) {
        if ((j & m) == 0) {
          float lo = v[j], hi = v[j + m];
          v[j] = lo + hi;
          v[j + m] = lo - hi;
        }
      }
    }
    const int g = tid & 7;
#pragma unroll
    for (int m = 1; m <= 4; m <<= 1) {
#pragma unroll
      for (int j = 0; j < 16; ++j) {
        float p = __shfl_xor(v[j], m, 64);
        v[j] = (g & m) ? (p - v[j]) : (v[j] + p);
      }
    }
    const float s = 0.08838834764831845f; // 1/sqrt(128)
#pragma unroll
    for (int j = 0; j < 16; ++j) v[j] *= s;
  }

  // row absmax: wave reduce then block reduce (4 waves)
  float am = 0.f;
#pragma unroll
  for (int j = 0; j < 16; ++j) am = fmaxf(am, fabsf(v[j]));
#pragma unroll
  for (int m = 1; m < 64; m <<= 1) am = fmaxf(am, __shfl_xor(am, m, 64));
  if ((tid & 63) == 0) red[tid >> 6] = am;
  __syncthreads();
  am = fmaxf(fmaxf(red[0], red[1]), fmaxf(red[2], red[3]));

  const float inv = (am > 1e-30f) ? (127.0f / am) : 0.f;
  union { uint4 u; signed char c[16]; } pk;
#pragma unroll
  for (int j = 0; j < 16; ++j) {
    float q = __builtin_rintf(v[j] * inv);
    q = fminf(127.f, fmaxf(-127.f, q));
    pk.c[j] = (signed char)(int)q;
  }
  signed char* dst = (isW ? Wq : Xq) + (size_t)row * Kd + tid * 16;
  *(uint4*)dst = pk.u;
  if (tid == 0) (isW ? sw : sx)[row] = am / 127.0f;
}

// ---------------------------------------------------------------------------
__device__ __forceinline__ void gload16(const void* g, void* l) {
  __builtin_amdgcn_global_load_lds((const AS1 unsigned int*)g,
                                   (AS3 unsigned int*)l, 16, 0, 0);
}

// ---------------------------------------------------------------------------
// Kernel 2: i8 GEMM. R0's proven geometry/staging/swizzle (256^2, 8 waves of
// 128x64, 16x16x64 MFMA, 0 bank conflicts) with the phase template rewritten
// to the m201-verified order:
//   {READS; STAGE; [vmcnt(6)]; BARRIER; lgkmcnt(0); setprio+16 MFMA; BARRIER}
// vs R0's {BARRIER; READS; STAGE; lgkm(6); MFMA}. Reads are issued BEFORE
// the barrier so the barrier-wait absorbs DS latency and the MFMA cluster
// starts with lgkm already drained (m196/m233: this is the proven lever at
// exactly this geometry -- 62% MfmaUtil on the bf16 twin). R3's earlier test
// of this order was on the 4-wave/2-block config (confounded); this is the
// first run at m201's own geometry.
//
// vmcnt ledger (simulated from prologue): stages 2 loads/phase; confirms at
// p0-tail (kh1 of tile t, read by p1) and p2-tail (kh0 of t+1, read by p3);
// outstanding oscillates 6-10, never drains to 0 in the loop. t=0's p0
// vmcnt(6) is an exact no-op (outstanding==6). Restage safety is stronger
// than R0: every plane's reads drain at that phase's lgkm(0) before the
// post-MFMA barrier; restages are >=2 barriers later.
// Dequant epilogue: out = sx[m]*sw[n]*acc + b[n] (integer accum is exact).
// ---------------------------------------------------------------------------
#define BM 256
#define BN 256
#define PL(base_, mat_, kh_) ((base_) + (((mat_) * 2 + (kh_)) * 16384))

__global__ __launch_bounds__(512, 2) void gemm256_i8(const signed char* __restrict__ Xq,
                                                     const signed char* __restrict__ Wq,
                                                     const float* __restrict__ sx,
                                                     const float* __restrict__ sw,
                                                     const float* __restrict__ bias,
                                                     float* __restrict__ out,
                                                     int M, int N, int K) {
  __shared__ __align__(16) char lds[131072];

  const int tid = threadIdx.x;
  const int lane = tid & 63;
  const int wid = tid >> 6; // 0..7
  const int wm = wid >> 2;  // 0..1
  const int wn = wid & 3;   // 0..3

  // XCD bijective swizzle (gridDim.x = 512, multiple of 8)
  const int nwg = gridDim.x;
  const int cpx = nwg >> 3;
  const int swz = (blockIdx.x & 7) * cpx + (blockIdx.x >> 3);
  const int nbn = N / BN;
  const int m0 = (swz / nbn) * BM;
  const int n0 = (swz % nbn) * BN;

  const size_t Kb = (size_t)K; // 1 byte/elem

  // ---- stage source pointers: pre-swizzled global (rule #21) ----
  const int dphys0 = tid * 16;
  const int dphys1 = tid * 16 + 8192;
  const char* srcA[2][2]; // [kh][rd]
  const char* srcB[2][2];
  {
    const int dv[2] = {dphys0, dphys1};
#pragma unroll
    for (int rd = 0; rd < 2; ++rd) {
      const int d = dv[rd];
      const int l = d ^ (((d >> 7) & 3) << 4); // involution: bits 7,8 untouched
      const int row = l >> 6;
      const int cb = l & 63;
#pragma unroll
      for (int kh = 0; kh < 2; ++kh) {
        srcA[kh][rd] = (const char*)Xq + (size_t)(m0 + row) * Kb + kh * 64 + cb;
        srcB[kh][rd] = (const char*)Wq + (size_t)(n0 + row) * Kb + kh * 64 + cb;
      }
    }
  }

  // ---- swizzled in-plane ds_read offsets (identical bytes to R0) ----
  const int q = lane >> 4;  // k-chunk 0..3 (16 B each = 16 i8)
  const int fr = lane & 15; // frag row
  int oA[2][4], oB[4];
#pragma unroll
  for (int mh = 0; mh < 2; ++mh)
#pragma unroll
    for (int mi = 0; mi < 4; ++mi) {
      int row = wm * 128 + mh * 64 + mi * 16 + fr;
      int byt = row * 64 + q * 16;
      oA[mh][mi] = byt ^ (((byt >> 7) & 3) << 4);
    }
#pragma unroll
  for (int ni = 0; ni < 4; ++ni) {
    int row = wn * 64 + ni * 16 + fr;
    int byt = row * 64 + q * 16;
    oB[ni] = byt ^ (((byt >> 7) & 3) << 4);
  }

  i32x4 acc[8][4];
#pragma unroll
  for (int i = 0; i < 8; ++i)
#pragma unroll
    for (int j = 0; j < 4; ++j) acc[i][j] = (i32x4){0, 0, 0, 0};

  const int NT = K / 128; // 32 (K-tile = 128 i8 = 128 B/row)
  char* const lb0 = lds;
  char* const lb1 = lds + 65536;

#define STAGE(mat_, kh_, base_, toff_)                                       \
  do {                                                                       \
    const char* s0_ = ((mat_) ? srcB : srcA)[kh_][0] + (toff_);              \
    const char* s1_ = ((mat_) ? srcB : srcA)[kh_][1] + (toff_);              \
    gload16(s0_, PL(base_, mat_, kh_) + dphys0);                             \
    gload16(s1_, PL(base_, mat_, kh_) + dphys1);                             \
  } while (0)

#define READ_A4(dst_, base_, kh_, mh_)                                       \
  do {                                                                       \
    const char* p_ = PL(base_, 0, kh_);                                      \
    _Pragma("unroll") for (int mi = 0; mi < 4; ++mi)                         \
        dst_[mi] = *(const i32x4*)(p_ + oA[mh_][mi]);                        \
  } while (0)

#define READ_B4(dst_, base_, kh_)                                            \
  do {                                                                       \
    const char* p_ = PL(base_, 1, kh_);                                      \
    _Pragma("unroll") for (int ni = 0; ni < 4; ++ni)                         \
        dst_[ni] = *(const i32x4*)(p_ + oB[ni]);                             \
  } while (0)

#define MFMA16(mh_, a_, b_)                                                  \
  do {                                                                       \
    __builtin_amdgcn_s_setprio(1);                                           \
    _Pragma("unroll") for (int mi = 0; mi < 4; ++mi)                         \
        _Pragma("unroll") for (int ni = 0; ni < 4; ++ni)                     \
            acc[(mh_)*4 + mi][ni] = __builtin_amdgcn_mfma_i32_16x16x64_i8(   \
                a_[mi], b_[ni], acc[(mh_)*4 + mi][ni], 0, 0, 0);             \
    __builtin_amdgcn_s_setprio(0);                                           \
    __builtin_amdgcn_sched_barrier(0);                                       \
  } while (0)

#define LGKM0()                                                              \
  asm volatile("s_waitcnt lgkmcnt(0)" ::: "memory");                         \
  __builtin_amdgcn_sched_barrier(0)

#define BARRIER()                                                            \
  __builtin_amdgcn_s_barrier();                                              \
  asm volatile("" ::: "memory")

  // ---- prologue: stage kh0(0), kh1(0), kh0(1) = 12 loads; confirm tile 0 ----
  gload16(srcA[0][0], PL(lb0, 0, 0) + dphys0);
  gload16(srcA[0][1], PL(lb0, 0, 0) + dphys1);
  gload16(srcB[0][0], PL(lb0, 1, 0) + dphys0);
  gload16(srcB[0][1], PL(lb0, 1, 0) + dphys1);
  gload16(srcA[1][0], PL(lb0, 0, 1) + dphys0);
  gload16(srcA[1][1], PL(lb0, 0, 1) + dphys1);
  gload16(srcB[1][0], PL(lb0, 1, 1) + dphys0);
  gload16(srcB[1][1], PL(lb0, 1, 1) + dphys1);
  gload16(srcA[0][0] + 128, PL(lb1, 0, 0) + dphys0);
  gload16(srcA[0][1] + 128, PL(lb1, 0, 0) + dphys1);
  gload16(srcB[0][0] + 128, PL(lb1, 1, 0) + dphys0);
  gload16(srcB[0][1] + 128, PL(lb1, 1, 0) + dphys1);
  asm volatile("s_waitcnt vmcnt(4)" ::: "memory"); // tile 0 fully landed
  BARRIER();

  i32x4 av0[4], av1[4], bv0[4], bv1[4];
  READ_A4(av0, lb0, 0, 0); // F0(0) A-frags
  READ_B4(bv0, lb0, 0);    // F0(0) B-frags

  for (int t = 0; t < NT; ++t) {
    char* const cb = (t & 1) ? lb1 : lb0; // current buffer
    char* const db = (t & 1) ? lb0 : lb1; // other buffer
    int tn1 = t + 1; if (tn1 >= NT) tn1 -= NT; // ring wrap
    int tn2 = t + 2; if (tn2 >= NT) tn2 -= NT;
    const size_t toff1 = (size_t)tn1 * 128; // 128 B per K-tile
    const size_t toff2 = (size_t)tn2 * 128;

    // p0: read F1 (A kh0 mh1); stage A-kh1(t+1)->d; vmcnt(6) confirms kh1(t)
    //     ahead of p1's reads; MFMA F0 (mh0 x kh0)
    READ_A4(av1, cb, 0, 1);
    STAGE(0, 1, db, toff1);
    asm volatile("s_waitcnt vmcnt(6)" ::: "memory");
    BARRIER();
    LGKM0();
    MFMA16(0, av0, bv0);
    BARRIER();

    // p1: read F2 (A kh1 mh0 + B kh1); stage B-kh1(t+1)->d; MFMA F1 (mh1 x kh0)
    READ_A4(av0, cb, 1, 0);
    READ_B4(bv1, cb, 1);
    STAGE(1, 1, db, toff1);
    BARRIER();
    LGKM0();
    MFMA16(1, av1, bv0);
    BARRIER();

    // p2: read F3 (A kh1 mh1); stage A-kh0(t+2)->c; vmcnt(6) confirms kh0(t+1)
    //     ahead of p3's reads; MFMA F2 (mh0 x kh1)
    READ_A4(av1, cb, 1, 1);
    STAGE(0, 0, cb, toff2);
    asm volatile("s_waitcnt vmcnt(6)" ::: "memory");
    BARRIER();
    LGKM0();
    MFMA16(0, av0, bv1);
    BARRIER();

    // p3: read F0(t+1) (A kh0 mh0 + B kh0, from buf d); stage B-kh0(t+2)->c;
    //     MFMA F3 (mh1 x kh1)
    READ_A4(av0, db, 0, 0);
    READ_B4(bv0, db, 0);
    STAGE(1, 0, cb, toff2);
    BARRIER();
    LGKM0();
    MFMA16(1, av1, bv1);
    BARRIER();
  }
  asm volatile("s_waitcnt vmcnt(0)" ::: "memory"); // drain ring stages

  // ---- epilogue: C/D col=lane&15, row=(lane>>4)*4+r (dtype-independent);
  // dequant out = sx[row]*sw[col]*acc + b[col], fp32 store.
  const int orow = m0 + wm * 128;
  const int ocol = n0 + wn * 64;
  const int rsub = q << 2;
#pragma unroll
  for (int ni = 0; ni < 4; ++ni) {
    const int col = ocol + ni * 16 + fr;
    const float swc = sw[col];
    const float bc = bias[col];
#pragma unroll
    for (int am = 0; am < 8; ++am) {
      const int rbase = orow + (am >> 2) * 64 + (am & 3) * 16 + rsub;
#pragma unroll
      for (int r = 0; r < 4; ++r) {
        const int row = rbase + r;
        out[(size_t)row * N + col] =
            (float)acc[am][ni][r] * (sx[row] * swc) + bc;
      }
    }
  }
#undef STAGE
#undef READ_A4
#undef READ_B4
#undef MFMA16
#undef LGKM0
#undef BARRIER
}

// ---------------------------------------------------------------------------
// Fallback (small workspace): bf16 path — standalone FWHT + 128^2 GEMM.
// ---------------------------------------------------------------------------
__global__ __launch_bounds__(256) void fwht_only(const float* __restrict__ W,
                                                 unsigned short* __restrict__ Wp,
                                                 int total_vec) {
  int t = blockIdx.x * blockDim.x + threadIdx.x;
  if (t >= total_vec) return;
  float4 r0 = ((const float4*)W)[2 * t];
  float4 r1 = ((const float4*)W)[2 * t + 1];
  float v[8] = {r0.x, r0.y, r0.z, r0.w, r1.x, r1.y, r1.z, r1.w};
#pragma unroll
  for (int m = 1; m <= 4; m <<= 1) {
#pragma unroll
    for (int j = 0; j < 8; ++j) {
      if ((j & m) == 0) {
        float lo = v[j], hi = v[j + m];
        v[j] = lo + hi;
        v[j + m] = lo - hi;
      }
    }
  }
  const int g = t & 15;
#pragma unroll
  for (int m = 1; m <= 8; m <<= 1) {
#pragma unroll
    for (int j = 0; j < 8; ++j) {
      float p = __shfl_xor(v[j], m, 64);
      v[j] = (g & m) ? (p - v[j]) : (v[j] + p);
    }
  }
  const float s = 0.08838834764831845f;
  uint4 outv;
  unsigned short* ou = (unsigned short*)&outv;
#pragma unroll
  for (int j = 0; j < 8; ++j) ou[j] = f2bf(v[j] * s);
  ((uint4*)Wp)[t] = outv;
}

__global__ __launch_bounds__(256) void gemm128_a32(const float* __restrict__ X,
                                                   const unsigned short* __restrict__ Wp,
                                                   const float* __restrict__ bias,
                                                   float* __restrict__ out,
                                                   int M, int N, int K) {
  __shared__ __align__(16) unsigned short lA[128 * 32];
  __shared__ __align__(16) unsigned short lB[128 * 32];
  const int tid = threadIdx.x;
  const int lane = tid & 63;
  const int wid = tid >> 6;
  const int wr = wid >> 1, wc = wid & 1;
  const int nbn = N / 128;
  const int bm = blockIdx.x / nbn, bn = blockIdx.x % nbn;
  const int m0 = bm * 128, n0 = bn * 128;
  f32x4 acc[4][4];
#pragma unroll
  for (int i = 0; i < 4; ++i)
#pragma unroll
    for (int j = 0; j < 4; ++j) acc[i][j] = (f32x4){0.f, 0.f, 0.f, 0.f};
  const size_t Kb = (size_t)K * 2;
  const int off0 = tid * 16, off1 = off0 + 4096;
  const int r0 = off0 >> 6, c0 = off0 & 63;
  const int r1 = off1 >> 6, c1 = off1 & 63;
  const char* Bg0 = (const char*)Wp + (size_t)(n0 + r0) * Kb + c0;
  const char* Bg1 = (const char*)Wp + (size_t)(n0 + r1) * Kb + c1;
  char* lB0 = (char*)lB + off0;
  char* lB1 = (char*)lB + off1;
  const int arow = tid >> 1;
  const int acol = (tid & 1) * 16;
  const float* Af = X + (size_t)(m0 + arow) * K + acol;
  unsigned short* lAw = &lA[arow * 32 + acol];
  const int fr = lane & 15;
  const int kc = (lane >> 4) << 3;
  const unsigned short* pA = &lA[(wr * 64 + fr) * 32 + kc];
  const unsigned short* pB = &lB[(wc * 64 + fr) * 32 + kc];
  for (int k0 = 0; k0 < K; k0 += 32) {
    const int kb = k0 << 1;
    gload16(Bg0 + kb, lB0);
    gload16(Bg1 + kb, lB1);
    const float* src = Af + k0;
    float4 f0 = *(const float4*)(src + 0);
    float4 f1 = *(const float4*)(src + 4);
    float4 f2 = *(const float4*)(src + 8);
    float4 f3 = *(const float4*)(src + 12);
    union { uint4 u[2]; unsigned short s[16]; } pk;
    float vv[16] = {f0.x, f0.y, f0.z, f0.w, f1.x, f1.y, f1.z, f1.w,
                    f2.x, f2.y, f2.z, f2.w, f3.x, f3.y, f3.z, f3.w};
#pragma unroll
    for (int j = 0; j < 16; ++j) pk.s[j] = f2bf(vv[j]);
    ((uint4*)lAw)[0] = pk.u[0];
    ((uint4*)(lAw + 8))[0] = pk.u[1];
    __syncthreads();
    short8 af[4], bfr[4];
#pragma unroll
    for (int mi = 0; mi < 4; ++mi) af[mi] = *(const short8*)(pA + mi * 16 * 32);
#pragma unroll
    for (int ni = 0; ni < 4; ++ni) bfr[ni] = *(const short8*)(pB + ni * 16 * 32);
#pragma unroll
    for (int mi = 0; mi < 4; ++mi)
#pragma unroll
      for (int ni = 0; ni < 4; ++ni)
        acc[mi][ni] = __builtin_amdgcn_mfma_f32_16x16x32_bf16(af[mi], bfr[ni],
                                                              acc[mi][ni], 0, 0, 0);
    __syncthreads();
  }
  const int orow0 = m0 + wr * 64;
  const int ocol0 = n0 + wc * 64;
  const int rsub = (lane >> 4) << 2;
#pragma unroll
  for (int ni = 0; ni < 4; ++ni) {
    const int col = ocol0 + ni * 16 + fr;
    const float bc = bias[col];
#pragma unroll
    for (int mi = 0; mi < 4; ++mi)
#pragma unroll
      for (int r = 0; r < 4; ++r)
        out[(size_t)(orow0 + mi * 16 + rsub + r) * N + col] = acc[mi][ni][r] + bc;
  }
}

// ---------------------------------------------------------------------------
extern "C" void kernel_launch(void* const* d_in, const int* in_sizes, int n_in,
                              void* d_out, int out_size, void* d_ws, size_t ws_size,
                              hipStream_t stream) {
  const float* x = (const float*)d_in[0];
  const float* W = (const float*)d_in[1];
  const float* b = (const float*)d_in[2];
  float* out = (float*)d_out;

  const int O = in_sizes[2];     // 4096
  const int K = in_sizes[1] / O; // 4096
  const int M = in_sizes[0] / K; // 8192

  const size_t wqB = (size_t)O * K;       // i8 W'
  const size_t xqB = (size_t)M * K;       // i8 x
  const size_t need = wqB + xqB + (size_t)(O + M) * 4 + 256;

  if (ws_size >= need) {
    signed char* Wq = (signed char*)d_ws;
    signed char* Xq = (signed char*)d_ws + wqB;
    float* sw = (float*)((char*)d_ws + wqB + xqB);
    float* sx = sw + O;
    quant_prep<<<O + M, 256, 0, stream>>>(W, Wq, sw, x, Xq, sx, O, K);
    dim3 grid((M / BM) * (O / BN)); // 32*16 = 512, %8 == 0
    gemm256_i8<<<grid, 512, 0, stream>>>(Xq, Wq, sx, sw, b, out, M, O, K);
  } else {
    unsigned short* Wp = (unsigned short*)d_ws;
    const int wvec = (O * K) / 8;
    fwht_only<<<(wvec + 255) / 256, 256, 0, stream>>>(W, Wp, wvec);
    dim3 grid((M / 128) * (O / 128));
    gemm128_a32<<<grid, 256, 0, stream>>>(x, Wp, b, out, M, O, K);
  }
}

// Round 8
// 194.199 us; speedup vs baseline: 1.0597x; 1.0211x over previous
//
#include <hip/hip_runtime.h>
#include <hip/hip_bf16.h>
#include <stdint.h>

#define AS1 __attribute__((address_space(1)))
#define AS3 __attribute__((address_space(3)))

typedef __attribute__((ext_vector_type(8))) short short8;
typedef __attribute__((ext_vector_type(4))) float f32x4;
typedef __attribute__((ext_vector_type(4))) int i32x4;

__device__ __forceinline__ unsigned short f2bf(float f) {
  return __builtin_bit_cast(unsigned short, __float2bfloat16(f));
}

// ---------------------------------------------------------------------------
// Kernel 1 (fused quant prep): one block per matrix row.
// Blocks [0, wrows): FWHT-128 on W row (fp32, in-register) -> row absmax ->
//   i8 quantize -> Wq, s_w[row].
// Blocks [wrows, ...): x row absmax -> i8 quantize -> Xq, s_x[row].
// 256 thr x 16 elems = 4096 elems/row. Exact per-row absmax => no clipping;
// error is pure rounding (~0.9% rms per element). ~80% of its 251 MB BW
// floor -- not the lever.
// ---------------------------------------------------------------------------
__global__ __launch_bounds__(256) void quant_prep(const float* __restrict__ W,
                                                  signed char* __restrict__ Wq,
                                                  float* __restrict__ sw,
                                                  const float* __restrict__ x,
                                                  signed char* __restrict__ Xq,
                                                  float* __restrict__ sx,
                                                  int wrows, int Kd) {
  __shared__ float red[4];
  const int bid = blockIdx.x;
  const int tid = threadIdx.x;
  const bool isW = bid < wrows;
  const int row = isW ? bid : bid - wrows;
  const float* src = (isW ? W : x) + (size_t)row * Kd + tid * 16;

  float v[16];
  {
    float4 f0 = ((const float4*)src)[0];
    float4 f1 = ((const float4*)src)[1];
    float4 f2 = ((const float4*)src)[2];
    float4 f3 = ((const float4*)src)[3];
    v[0] = f0.x; v[1] = f0.y; v[2] = f0.z; v[3] = f0.w;
    v[4] = f1.x; v[5] = f1.y; v[6] = f1.z; v[7] = f1.w;
    v[8] = f2.x; v[9] = f2.y; v[10] = f2.z; v[11] = f2.w;
    v[12] = f3.x; v[13] = f3.y; v[14] = f3.z; v[15] = f3.w;
  }

  if (isW) {
    // FWHT-128: thread holds 16 contiguous elems (bits 0..3); a 128-segment
    // spans 8 threads (bits 4..6 = tid&7), all within one wave.
#pragma unroll
    for (int m = 1; m <= 8; m <<= 1) {
#pragma unroll
      for (int j = 0; j < 16; ++j) {
        if ((j & m) == 0) {
          float lo = v[j], hi = v[j + m];
          v[j] = lo + hi;
          v[j + m] = lo - hi;
        }
      }
    }
    const int g = tid & 7;
#pragma unroll
    for (int m = 1; m <= 4; m <<= 1) {
#pragma unroll
      for (int j = 0; j < 16; ++j) {
        float p = __shfl_xor(v[j], m, 64);
        v[j] = (g & m) ? (p - v[j]) : (v[j] + p);
      }
    }
    const float s = 0.08838834764831845f; // 1/sqrt(128)
#pragma unroll
    for (int j = 0; j < 16; ++j) v[j] *= s;
  }

  // row absmax: wave reduce then block reduce (4 waves)
  float am = 0.f;
#pragma unroll
  for (int j = 0; j < 16; ++j) am = fmaxf(am, fabsf(v[j]));
#pragma unroll
  for (int m = 1; m < 64; m <<= 1) am = fmaxf(am, __shfl_xor(am, m, 64));
  if ((tid & 63) == 0) red[tid >> 6] = am;
  __syncthreads();
  am = fmaxf(fmaxf(red[0], red[1]), fmaxf(red[2], red[3]));

  const float inv = (am > 1e-30f) ? (127.0f / am) : 0.f;
  union { uint4 u; signed char c[16]; } pk;
#pragma unroll
  for (int j = 0; j < 16; ++j) {
    float q = __builtin_rintf(v[j] * inv);
    q = fminf(127.f, fmaxf(-127.f, q));
    pk.c[j] = (signed char)(int)q;
  }
  signed char* dst = (isW ? Wq : Xq) + (size_t)row * Kd + tid * 16;
  *(uint4*)dst = pk.u;
  if (tid == 0) (isW ? sw : sx)[row] = am / 127.0f;
}

// ---------------------------------------------------------------------------
__device__ __forceinline__ void gload16(const void* g, void* l) {
  __builtin_amdgcn_global_load_lds((const AS1 unsigned int*)g,
                                   (AS3 unsigned int*)l, 16, 0, 0);
}

// ---------------------------------------------------------------------------
// Kernel 2: i8 GEMM -- SESSION-BEST (R0), restored byte-for-byte.
//
// Verified empirical optimum of a 7-variant search (this session):
//   R0 143.5us/42.8% > R7 m201-order 149 > R2 counted-lgkm-4w 155.7 >
//   R6 32x32-shape 156.2 > R1 R-M-B-4w 156.4 > R5 bigwave-ILP 159.9 >
//   R3 R-B-M-B-4w 166.4.
// Occupancy 11->40%, 4 barrier orders, counted lgkm/vmcnt ledgers, in-wave
// operand double-buffering, both i8 MFMA shapes: response surface is flat-
// to-negative around this schedule. Mechanism (R2/R5 arithmetic): per-phase
// time == DS-cycles + MFMA-cycles in every variant (LDS<->MFMA serialized);
// effective in-kernel i8 rate ~1.9 POPS vs 3.94 POPS isolated ubench --
// same in-kernel-vs-ubench ratio class as the bf16 record kernels (m201
// 1563/2495). Breaking it requires the hand-asm 1:1 MFMA<->load interleave
// class (AITER), not reachable from HIP source in this session's attempts.
//
// Structure: 256x256 tile, 8 waves of 128x64, planes [256 rows][64 B],
// K-tile = 2 planes = 128 K, NT = 32. mfma_i32_16x16x64_i8. XOR involution
// on pre-swizzled global stage sources AND ds_read offsets (rule #21; 0
// bank conflicts measured). vmcnt/lgkm ledger: 2 stages/phase, vmcnt(6)
// confirms at p1/p3 heads; LGKM(4/8) gates reads-ahead; never drains to 0.
// Dequant epilogue: out = sx[m]*sw[n]*acc + b[n] (integer accum is exact).
// ---------------------------------------------------------------------------
#define BM 256
#define BN 256
#define PL(base_, mat_, kh_) ((base_) + (((mat_) * 2 + (kh_)) * 16384))

__global__ __launch_bounds__(512, 2) void gemm256_i8(const signed char* __restrict__ Xq,
                                                     const signed char* __restrict__ Wq,
                                                     const float* __restrict__ sx,
                                                     const float* __restrict__ sw,
                                                     const float* __restrict__ bias,
                                                     float* __restrict__ out,
                                                     int M, int N, int K) {
  __shared__ __align__(16) char lds[131072];

  const int tid = threadIdx.x;
  const int lane = tid & 63;
  const int wid = tid >> 6; // 0..7
  const int wm = wid >> 2;  // 0..1
  const int wn = wid & 3;   // 0..3

  // XCD bijective swizzle (gridDim.x = 512, multiple of 8)
  const int nwg = gridDim.x;
  const int cpx = nwg >> 3;
  const int swz = (blockIdx.x & 7) * cpx + (blockIdx.x >> 3);
  const int nbn = N / BN;
  const int m0 = (swz / nbn) * BM;
  const int n0 = (swz % nbn) * BN;

  const size_t Kb = (size_t)K; // 1 byte/elem

  // ---- stage source pointers: pre-swizzled global (rule #21) ----
  const int dphys0 = tid * 16;
  const int dphys1 = tid * 16 + 8192;
  const char* srcA[2][2]; // [kh][rd]
  const char* srcB[2][2];
  {
    const int dv[2] = {dphys0, dphys1};
#pragma unroll
    for (int rd = 0; rd < 2; ++rd) {
      const int d = dv[rd];
      const int l = d ^ (((d >> 7) & 3) << 4); // involution: bits 7,8 untouched
      const int row = l >> 6;
      const int cb = l & 63;
#pragma unroll
      for (int kh = 0; kh < 2; ++kh) {
        srcA[kh][rd] = (const char*)Xq + (size_t)(m0 + row) * Kb + kh * 64 + cb;
        srcB[kh][rd] = (const char*)Wq + (size_t)(n0 + row) * Kb + kh * 64 + cb;
      }
    }
  }

  // ---- swizzled in-plane ds_read offsets ----
  const int q = lane >> 4;  // k-chunk 0..3 (16 B each = 16 i8)
  const int fr = lane & 15; // frag row
  int oA[2][4], oB[4];
#pragma unroll
  for (int mh = 0; mh < 2; ++mh)
#pragma unroll
    for (int mi = 0; mi < 4; ++mi) {
      int row = wm * 128 + mh * 64 + mi * 16 + fr;
      int byt = row * 64 + q * 16;
      oA[mh][mi] = byt ^ (((byt >> 7) & 3) << 4);
    }
#pragma unroll
  for (int ni = 0; ni < 4; ++ni) {
    int row = wn * 64 + ni * 16 + fr;
    int byt = row * 64 + q * 16;
    oB[ni] = byt ^ (((byt >> 7) & 3) << 4);
  }

  i32x4 acc[8][4];
#pragma unroll
  for (int i = 0; i < 8; ++i)
#pragma unroll
    for (int j = 0; j < 4; ++j) acc[i][j] = (i32x4){0, 0, 0, 0};

  const int NT = K / 128; // 32 (K-tile = 128 i8 = 128 B/row)
  char* const lb0 = lds;
  char* const lb1 = lds + 65536;

#define STAGE(mat_, kh_, base_, toff_)                                       \
  do {                                                                       \
    const char* s0_ = ((mat_) ? srcB : srcA)[kh_][0] + (toff_);              \
    const char* s1_ = ((mat_) ? srcB : srcA)[kh_][1] + (toff_);              \
    gload16(s0_, PL(base_, mat_, kh_) + dphys0);                             \
    gload16(s1_, PL(base_, mat_, kh_) + dphys1);                             \
  } while (0)

#define READ_A4(dst_, base_, kh_, mh_)                                       \
  do {                                                                       \
    const char* p_ = PL(base_, 0, kh_);                                      \
    _Pragma("unroll") for (int mi = 0; mi < 4; ++mi)                         \
        dst_[mi] = *(const i32x4*)(p_ + oA[mh_][mi]);                        \
  } while (0)

#define READ_B4(dst_, base_, kh_)                                            \
  do {                                                                       \
    const char* p_ = PL(base_, 1, kh_);                                      \
    _Pragma("unroll") for (int ni = 0; ni < 4; ++ni)                         \
        dst_[ni] = *(const i32x4*)(p_ + oB[ni]);                             \
  } while (0)

#define MFMA16(mh_, a_, b_)                                                  \
  do {                                                                       \
    __builtin_amdgcn_s_setprio(1);                                           \
    _Pragma("unroll") for (int mi = 0; mi < 4; ++mi)                         \
        _Pragma("unroll") for (int ni = 0; ni < 4; ++ni)                     \
            acc[(mh_)*4 + mi][ni] = __builtin_amdgcn_mfma_i32_16x16x64_i8(   \
                a_[mi], b_[ni], acc[(mh_)*4 + mi][ni], 0, 0, 0);             \
    __builtin_amdgcn_s_setprio(0);                                           \
    __builtin_amdgcn_sched_barrier(0);                                       \
  } while (0)

#define LGKM(n_)                                                             \
  asm volatile("s_waitcnt lgkmcnt(" #n_ ")" ::: "memory");                   \
  __builtin_amdgcn_sched_barrier(0)

  // ---- prologue: stage kh0(0), kh1(0), kh0(1) = 12 loads; confirm tile 0 ----
  gload16(srcA[0][0], PL(lb0, 0, 0) + dphys0);
  gload16(srcA[0][1], PL(lb0, 0, 0) + dphys1);
  gload16(srcB[0][0], PL(lb0, 1, 0) + dphys0);
  gload16(srcB[0][1], PL(lb0, 1, 0) + dphys1);
  gload16(srcA[1][0], PL(lb0, 0, 1) + dphys0);
  gload16(srcA[1][1], PL(lb0, 0, 1) + dphys1);
  gload16(srcB[1][0], PL(lb0, 1, 1) + dphys0);
  gload16(srcB[1][1], PL(lb0, 1, 1) + dphys1);
  gload16(srcA[0][0] + 128, PL(lb1, 0, 0) + dphys0);
  gload16(srcA[0][1] + 128, PL(lb1, 0, 0) + dphys1);
  gload16(srcB[0][0] + 128, PL(lb1, 1, 0) + dphys0);
  gload16(srcB[0][1] + 128, PL(lb1, 1, 0) + dphys1);
  asm volatile("s_waitcnt vmcnt(4)" ::: "memory"); // tile 0 fully landed
  __builtin_amdgcn_s_barrier();
  asm volatile("" ::: "memory");

  i32x4 av0[4], av1[4], bv0[4], bv1[4];
  READ_A4(av0, lb0, 0, 0); // F0(0) A-frags
  READ_B4(bv0, lb0, 0);    // F0(0) B-frags

  for (int t = 0; t < NT; ++t) {
    char* const cb = (t & 1) ? lb1 : lb0; // current buffer
    char* const db = (t & 1) ? lb0 : lb1; // other buffer
    int tn1 = t + 1; if (tn1 >= NT) tn1 -= NT; // ring wrap
    int tn2 = t + 2; if (tn2 >= NT) tn2 -= NT;
    const size_t toff1 = (size_t)tn1 * 128; // 128 B per K-tile
    const size_t toff2 = (size_t)tn2 * 128;

    // p0: MFMA F0(av0,bv0); read F1->av1; stage A-kh1(t+1)->d
    __builtin_amdgcn_s_barrier();
    asm volatile("" ::: "memory");
    READ_A4(av1, cb, 0, 1);
    STAGE(0, 1, db, toff1);
    LGKM(4);
    MFMA16(0, av0, bv0);

    // p1: vmcnt(6) confirms kh1(t); read F2->av0,bv1; stage B-kh1(t+1)->d
    asm volatile("s_waitcnt vmcnt(6)" ::: "memory");
    __builtin_amdgcn_s_barrier();
    asm volatile("" ::: "memory");
    READ_A4(av0, cb, 1, 0);
    READ_B4(bv1, cb, 1);
    STAGE(1, 1, db, toff1);
    LGKM(8);
    MFMA16(1, av1, bv0);

    // p2: read F3->av1; stage A-kh0(t+2)->c (kh0 reads done by p1's lgkm)
    __builtin_amdgcn_s_barrier();
    asm volatile("" ::: "memory");
    READ_A4(av1, cb, 1, 1);
    STAGE(0, 0, cb, toff2);
    LGKM(4);
    MFMA16(0, av0, bv1);

    // p3: vmcnt(6) confirms kh0(t+1); read F0(t+1)->av0,bv0 from buf d
    asm volatile("s_waitcnt vmcnt(6)" ::: "memory");
    __builtin_amdgcn_s_barrier();
    asm volatile("" ::: "memory");
    READ_A4(av0, db, 0, 0);
    READ_B4(bv0, db, 0);
    STAGE(1, 0, cb, toff2);
    LGKM(8);
    MFMA16(1, av1, bv1);
  }
  asm volatile("s_waitcnt vmcnt(0)" ::: "memory"); // drain ring stages

  // ---- epilogue: C/D col=lane&15, row=(lane>>4)*4+r (dtype-independent);
  // dequant out = sx[row]*sw[col]*acc + b[col], fp32 store.
  const int orow = m0 + wm * 128;
  const int ocol = n0 + wn * 64;
  const int rsub = q << 2;
#pragma unroll
  for (int ni = 0; ni < 4; ++ni) {
    const int col = ocol + ni * 16 + fr;
    const float swc = sw[col];
    const float bc = bias[col];
#pragma unroll
    for (int am = 0; am < 8; ++am) {
      const int rbase = orow + (am >> 2) * 64 + (am & 3) * 16 + rsub;
#pragma unroll
      for (int r = 0; r < 4; ++r) {
        const int row = rbase + r;
        out[(size_t)row * N + col] =
            (float)acc[am][ni][r] * (sx[row] * swc) + bc;
      }
    }
  }
#undef STAGE
#undef READ_A4
#undef READ_B4
#undef MFMA16
#undef LGKM
}

// ---------------------------------------------------------------------------
// Fallback (small workspace): bf16 path — standalone FWHT + 128^2 GEMM.
// ---------------------------------------------------------------------------
__global__ __launch_bounds__(256) void fwht_only(const float* __restrict__ W,
                                                 unsigned short* __restrict__ Wp,
                                                 int total_vec) {
  int t = blockIdx.x * blockDim.x + threadIdx.x;
  if (t >= total_vec) return;
  float4 r0 = ((const float4*)W)[2 * t];
  float4 r1 = ((const float4*)W)[2 * t + 1];
  float v[8] = {r0.x, r0.y, r0.z, r0.w, r1.x, r1.y, r1.z, r1.w};
#pragma unroll
  for (int m = 1; m <= 4; m <<= 1) {
#pragma unroll
    for (int j = 0; j < 8; ++j) {
      if ((j & m) == 0) {
        float lo = v[j], hi = v[j + m];
        v[j] = lo + hi;
        v[j + m] = lo - hi;
      }
    }
  }
  const int g = t & 15;
#pragma unroll
  for (int m = 1; m <= 8; m <<= 1) {
#pragma unroll
    for (int j = 0; j < 8; ++j) {
      float p = __shfl_xor(v[j], m, 64);
      v[j] = (g & m) ? (p - v[j]) : (v[j] + p);
    }
  }
  const float s = 0.08838834764831845f;
  uint4 outv;
  unsigned short* ou = (unsigned short*)&outv;
#pragma unroll
  for (int j = 0; j < 8; ++j) ou[j] = f2bf(v[j] * s);
  ((uint4*)Wp)[t] = outv;
}

__global__ __launch_bounds__(256) void gemm128_a32(const float* __restrict__ X,
                                                   const unsigned short* __restrict__ Wp,
                                                   const float* __restrict__ bias,
                                                   float* __restrict__ out,
                                                   int M, int N, int K) {
  __shared__ __align__(16) unsigned short lA[128 * 32];
  __shared__ __align__(16) unsigned short lB[128 * 32];
  const int tid = threadIdx.x;
  const int lane = tid & 63;
  const int wid = tid >> 6;
  const int wr = wid >> 1, wc = wid & 1;
  const int nbn = N / 128;
  const int bm = blockIdx.x / nbn, bn = blockIdx.x % nbn;
  const int m0 = bm * 128, n0 = bn * 128;
  f32x4 acc[4][4];
#pragma unroll
  for (int i = 0; i < 4; ++i)
#pragma unroll
    for (int j = 0; j < 4; ++j) acc[i][j] = (f32x4){0.f, 0.f, 0.f, 0.f};
  const size_t Kb = (size_t)K * 2;
  const int off0 = tid * 16, off1 = off0 + 4096;
  const int r0 = off0 >> 6, c0 = off0 & 63;
  const int r1 = off1 >> 6, c1 = off1 & 63;
  const char* Bg0 = (const char*)Wp + (size_t)(n0 + r0) * Kb + c0;
  const char* Bg1 = (const char*)Wp + (size_t)(n0 + r1) * Kb + c1;
  char* lB0 = (char*)lB + off0;
  char* lB1 = (char*)lB + off1;
  const int arow = tid >> 1;
  const int acol = (tid & 1) * 16;
  const float* Af = X + (size_t)(m0 + arow) * K + acol;
  unsigned short* lAw = &lA[arow * 32 + acol];
  const int fr = lane & 15;
  const int kc = (lane >> 4) << 3;
  const unsigned short* pA = &lA[(wr * 64 + fr) * 32 + kc];
  const unsigned short* pB = &lB[(wc * 64 + fr) * 32 + kc];
  for (int k0 = 0; k0 < K; k0 += 32) {
    const int kb = k0 << 1;
    gload16(Bg0 + kb, lB0);
    gload16(Bg1 + kb, lB1);
    const float* src = Af + k0;
    float4 f0 = *(const float4*)(src + 0);
    float4 f1 = *(const float4*)(src + 4);
    float4 f2 = *(const float4*)(src + 8);
    float4 f3 = *(const float4*)(src + 12);
    union { uint4 u[2]; unsigned short s[16]; } pk;
    float vv[16] = {f0.x, f0.y, f0.z, f0.w, f1.x, f1.y, f1.z, f1.w,
                    f2.x, f2.y, f2.z, f2.w, f3.x, f3.y, f3.z, f3.w};
#pragma unroll
    for (int j = 0; j < 16; ++j) pk.s[j] = f2bf(vv[j]);
    ((uint4*)lAw)[0] = pk.u[0];
    ((uint4*)(lAw + 8))[0] = pk.u[1];
    __syncthreads();
    short8 af[4], bfr[4];
#pragma unroll
    for (int mi = 0; mi < 4; ++mi) af[mi] = *(const short8*)(pA + mi * 16 * 32);
#pragma unroll
    for (int ni = 0; ni < 4; ++ni) bfr[ni] = *(const short8*)(pB + ni * 16 * 32);
#pragma unroll
    for (int mi = 0; mi < 4; ++mi)
#pragma unroll
      for (int ni = 0; ni < 4; ++ni)
        acc[mi][ni] = __builtin_amdgcn_mfma_f32_16x16x32_bf16(af[mi], bfr[ni],
                                                              acc[mi][ni], 0, 0, 0);
    __syncthreads();
  }
  const int orow0 = m0 + wr * 64;
  const int ocol0 = n0 + wc * 64;
  const int rsub = (lane >> 4) << 2;
#pragma unroll
  for (int ni = 0; ni < 4; ++ni) {
    const int col = ocol0 + ni * 16 + fr;
    const float bc = bias[col];
#pragma unroll
    for (int mi = 0; mi < 4; ++mi)
#pragma unroll
      for (int r = 0; r < 4; ++r)
        out[(size_t)(orow0 + mi * 16 + rsub + r) * N + col] = acc[mi][ni][r] + bc;
  }
}

// ---------------------------------------------------------------------------
extern "C" void kernel_launch(void* const* d_in, const int* in_sizes, int n_in,
                              void* d_out, int out_size, void* d_ws, size_t ws_size,
                              hipStream_t stream) {
  const float* x = (const float*)d_in[0];
  const float* W = (const float*)d_in[1];
  const float* b = (const float*)d_in[2];
  float* out = (float*)d_out;

  const int O = in_sizes[2];     // 4096
  const int K = in_sizes[1] / O; // 4096
  const int M = in_sizes[0] / K; // 8192

  const size_t wqB = (size_t)O * K;       // i8 W'
  const size_t xqB = (size_t)M * K;       // i8 x
  const size_t need = wqB + xqB + (size_t)(O + M) * 4 + 256;

  if (ws_size >= need) {
    signed char* Wq = (signed char*)d_ws;
    signed char* Xq = (signed char*)d_ws + wqB;
    float* sw = (float*)((char*)d_ws + wqB + xqB);
    float* sx = sw + O;
    quant_prep<<<O + M, 256, 0, stream>>>(W, Wq, sw, x, Xq, sx, O, K);
    dim3 grid((M / BM) * (O / BN));
    gemm256_i8<<<grid, 512, 0, stream>>>(Xq, Wq, sx, sw, b, out, M, O, K);
  } else {
    unsigned short* Wp = (unsigned short*)d_ws;
    const int wvec = (O * K) / 8;
    fwht_only<<<(wvec + 255) / 256, 256, 0, stream>>>(W, Wp, wvec);
    dim3 grid((M / 128) * (O / 128));
    gemm128_a32<<<grid, 256, 0, stream>>>(x, Wp, b, out, M, O, K);
  }
}